// Round 3
// baseline (1263.443 us; speedup 1.0000x reference)
//
#include <hip/hip_runtime.h>

#define HH 1024
#define WW 2048
#define NN (HH*WW)
#define GRID 512
#define BLOCK 256
#define PXT (NN/(GRID*BLOCK))   // 16 pixels per thread
#define CHUNK (NN/GRID)         // 4096 pixels per block

struct Coord {
  int arr[GRID];                 // arrival tokens (one slot per block)
  int flag;                      // release token
  int pad0[15];
  int sidx; float sval; int psum; int inter; int uncl;  // published results
  int pad1[11];
  float pval[GRID]; int pidx[GRID];                     // argmax partials
  int psA[GRID]; int inA[GRID]; int unA[GRID];          // sum partials
};

// XLA expands logistic(x) as 0.5 + 0.5*tanh(0.5*x) — match that boundary.
__device__ __forceinline__ float sigmoid_ref(float x) {
  #pragma clang fp contract(off)
  return 0.5f + 0.5f * tanhf(0.5f * x);
}

__device__ __forceinline__ void arrive_store(Coord* c, int b, int tok) {
  __syncthreads();
  __threadfence();   // agent release: flush this block's writes to coherence point
  if (threadIdx.x == 0)
    __hip_atomic_store(&c->arr[b], tok, __ATOMIC_RELAXED, __HIP_MEMORY_SCOPE_AGENT);
}

__device__ __forceinline__ void wait_release(Coord* c, int tok) {
  if (threadIdx.x == 0)
    while (__hip_atomic_load(&c->flag, __ATOMIC_RELAXED, __HIP_MEMORY_SCOPE_AGENT) < tok)
      __builtin_amdgcn_s_sleep(1);
  __syncthreads();
  __threadfence();   // agent acquire: invalidate stale lines before reading pub data
}

__device__ __forceinline__ void gather_slots(Coord* c, int tok) {
  int t = threadIdx.x;
  for (int s = t; s < GRID; s += BLOCK)
    while (__hip_atomic_load(&c->arr[s], __ATOMIC_RELAXED, __HIP_MEMORY_SCOPE_AGENT) < tok)
      __builtin_amdgcn_s_sleep(1);
  __syncthreads();
  __threadfence();   // acquire before reading payload arrays
}

// barrier after phase B: reduce psum/inter partials, publish totals
__device__ void bar_B(Coord* c, int b, int tok, int lps, int lin, int* sa, int* sb) {
  if (threadIdx.x == 0) { c->psA[b] = lps; c->inA[b] = lin; }
  arrive_store(c, b, tok);
  if (b == 0) {
    gather_slots(c, tok);
    int t = threadIdx.x;
    sa[t] = c->psA[t] + c->psA[t + BLOCK];
    sb[t] = c->inA[t] + c->inA[t + BLOCK];
    __syncthreads();
    for (int off = BLOCK / 2; off; off >>= 1) {
      if (t < off) { sa[t] += sa[t + off]; sb[t] += sb[t + off]; }
      __syncthreads();
    }
    if (t == 0) {
      c->psum = sa[0]; c->inter = sb[0];
      __threadfence();
      __hip_atomic_store(&c->flag, tok, __ATOMIC_RELAXED, __HIP_MEMORY_SCOPE_AGENT);
    }
  }
  wait_release(c, tok);
}

// barrier after phase C / stage 1: reduce argmax + uncl count, publish
__device__ void bar_C(Coord* c, int b, int tok, float mv, int mi, int mu,
                      float* sv, int* si, int* sa) {
  if (threadIdx.x == 0) { c->pval[b] = mv; c->pidx[b] = mi; c->unA[b] = mu; }
  arrive_store(c, b, tok);
  if (b == 0) {
    gather_slots(c, tok);
    int t = threadIdx.x;
    float v1 = c->pval[t];         int i1 = c->pidx[t];
    float v2 = c->pval[t + BLOCK]; int i2 = c->pidx[t + BLOCK];
    int u = c->unA[t] + c->unA[t + BLOCK];
    if (v2 > v1 || (v2 == v1 && i2 < i1)) { v1 = v2; i1 = i2; }
    sv[t] = v1; si[t] = i1; sa[t] = u;
    __syncthreads();
    for (int off = BLOCK / 2; off; off >>= 1) {
      if (t < off) {
        float v = sv[t + off]; int ix = si[t + off];
        if (v > sv[t] || (v == sv[t] && ix < si[t])) { sv[t] = v; si[t] = ix; }
        sa[t] += sa[t + off];
      }
      __syncthreads();
    }
    if (t == 0) {
      c->sval = sv[0]; c->sidx = si[0]; c->uncl = sa[0];
      __threadfence();
      __hip_atomic_store(&c->flag, tok, __ATOMIC_RELAXED, __HIP_MEMORY_SCOPE_AGENT);
    }
  }
  wait_release(c, tok);
}

__global__ void init_kernel(Coord* c) {
  int t = threadIdx.x;
  for (int s = t; s < GRID; s += blockDim.x) c->arr[s] = 0;
  if (t == 0) c->flag = 0;
}

__global__ __launch_bounds__(BLOCK, 2)
void cluster_kernel(const float* __restrict__ pred,
                    int* __restrict__ out,
                    unsigned char* __restrict__ flags,   // bit0=mask bit1=uncl bit2=prop
                    Coord* __restrict__ c)
{
  #pragma clang fp contract(off)
  const int b = blockIdx.x, t = threadIdx.x;
  const int base = b * CHUNK;

  __shared__ float sv[BLOCK];
  __shared__ int   si[BLOCK];
  __shared__ int   sa[BLOCK];
  __shared__ int   sb[BLOCK];

  const float xstep = 2.0f / 2047.0f;   // jnp.linspace(0,2,2048) step, f32
  const float ystep = 1.0f / 1023.0f;   // jnp.linspace(0,1,1024) step, f32

  int tok = 1;

  // ---- stage 1: init flags/out, first argmax partials, mask count ----
  {
    float bv = -1.0f; int bi = 0; int mcount = 0;
    for (int k = 0; k < PXT; ++k) {
      int i = base + t + k * BLOCK;
      float seed = sigmoid_ref(pred[6 * NN + i]);
      int m = (seed > 0.5f) ? 1 : 0;
      flags[i] = (unsigned char)(m * 3);   // mask | uncl
      out[i] = 0;
      mcount += m;
      float sc = m ? seed : 0.0f;
      if (sc > bv) { bv = sc; bi = i; }    // i increasing -> first max kept
    }
    sv[t] = bv; si[t] = bi; sa[t] = mcount; __syncthreads();
    for (int off = BLOCK / 2; off; off >>= 1) {
      if (t < off) {
        float v = sv[t + off]; int ix = si[t + off];
        if (v > sv[t] || (v == sv[t] && ix < si[t])) { sv[t] = v; si[t] = ix; }
        sa[t] += sa[t + off];
      }
      __syncthreads();
    }
    bar_C(c, b, tok, sv[0], si[0], sa[0], sv, si, sa); tok++;
  }

  // ---- main greedy loop ----
  int count = 1;
  for (int it = 0; it < 4096; ++it) {
    int   uncl_tot = c->uncl;
    float sval     = c->sval;
    int   sidx     = c->sidx;
    if (uncl_tot <= 160) break;          // cond: uncl.sum() > min_pixel
    if (!(sval >= 0.5f)) break;          // go==false -> stop, no state change

    // center + sigma at seed pixel (pred is read-only: always fresh)
    int scol = sidx & (WW - 1), srow = sidx >> 11;
    float cx = tanhf(pred[sidx])      + xstep * (float)scol;
    float cy = tanhf(pred[NN + sidx]) + ystep * (float)srow;
    float s0 = expf(pred[2 * NN + sidx] * 10.0f);
    float s1 = expf(pred[3 * NN + sidx] * 10.0f);

    // ======== phase B: proposal + psum/inter ========
    int lps = 0, lin = 0;
    for (int k = 0; k < PXT; ++k) {
      int i = base + t + k * BLOCK;
      float ex = tanhf(pred[i])      + xstep * (float)(i & (WW - 1));
      float ey = tanhf(pred[NN + i]) + ystep * (float)(i >> 11);
      float dx = ex - cx, dy = ey - cy;
      float dsq = (dx * dx) * s0 + (dy * dy) * s1;
      float dist = expf(-dsq);
      unsigned char f = flags[i];
      int pr = ((dist > 0.5f) ? 1 : 0) & (f & 1);
      unsigned char f2 = (unsigned char)((f & 3) | (pr << 2));
      if (f2 != f) flags[i] = f2;        // write only on change (dirty-line diet)
      lps += pr;
      lin += (pr && ((f >> 1) & 1) && (i != sidx)) ? 1 : 0;  // uncl2 & proposal
    }
    sa[t] = lps; sb[t] = lin; __syncthreads();
    for (int off = BLOCK / 2; off; off >>= 1) {
      if (t < off) { sa[t] += sa[t + off]; sb[t] += sb[t + off]; }
      __syncthreads();
    }
    bar_B(c, b, tok, sa[0], sb[0], sa, sb); tok++;

    // ======== phase C: accept, labels, uncl update, next argmax ========
    int psum  = c->psum;
    int inter = c->inter;
    bool accept = (psum > 160) &&
                  ((float)inter / (float)(psum > 1 ? psum : 1) > 0.5f);

    int lu = 0;
    float bv = -1.0f; int bi = 0;
    for (int k = 0; k < PXT; ++k) {
      int i = base + t + k * BLOCK;
      unsigned char f = flags[i];
      int pr = (f >> 2) & 1;
      int u  = (f >> 1) & 1;
      int nu = (u && !pr && (i != sidx)) ? 1 : 0;
      unsigned char f2 = (unsigned char)((f & 5) | (nu << 1));  // keep mask+prop
      if (f2 != f) flags[i] = f2;
      lu += nu;
      if (accept && pr) out[i] = count;
      if (nu) {
        float seed = sigmoid_ref(pred[6 * NN + i]);
        if (seed > bv) { bv = seed; bi = i; }  // i increasing -> first max kept
      }
    }
    count += accept ? 1 : 0;

    sv[t] = bv; si[t] = bi; sa[t] = lu; __syncthreads();
    for (int off = BLOCK / 2; off; off >>= 1) {
      if (t < off) {
        float v = sv[t + off]; int ix = si[t + off];
        if (v > sv[t] || (v == sv[t] && ix < si[t])) { sv[t] = v; si[t] = ix; }
        sa[t] += sa[t + off];
      }
      __syncthreads();
    }
    bar_C(c, b, tok, sv[0], si[0], sa[0], sv, si, sa); tok++;
  }
}

extern "C" void kernel_launch(void* const* d_in, const int* in_sizes, int n_in,
                              void* d_out, int out_size, void* d_ws, size_t ws_size,
                              hipStream_t stream) {
  const float* pred = (const float*)d_in[0];
  int* out = (int*)d_out;

  char* ws = (char*)d_ws;
  unsigned char* flags = (unsigned char*)ws;        // NN bytes
  Coord* c = (Coord*)(ws + NN);                     // barrier + reduce state

  init_kernel<<<1, 256, 0, stream>>>(c);

  void* args[] = { (void*)&pred, (void*)&out, (void*)&flags, (void*)&c };
  hipLaunchCooperativeKernel((const void*)cluster_kernel, dim3(GRID), dim3(BLOCK),
                             args, 0, stream);
}

// Round 6
// 444.754 us; speedup vs baseline: 2.8408x; 2.8408x over previous
//
#include <hip/hip_runtime.h>

#define HH 1024
#define WW 2048
#define NN (HH*WW)
#define GRID 512
#define BLOCK 256
#define PXT 16
#define CHUNK (PXT*BLOCK)       // 4096 pixels per block

struct Coord {
  int arr[GRID];                // arrival tokens (one per block)
  int pad0[16];
  int flag;                     // release token
  int pad1[15];
  // published results (block 0 writes before releasing flag)
  int sidx; float sval; int psum; int inter; int uncl;
  float cx, cy, s0, s1;
  int pad2[7];
  // reduction payload slots
  float pval[GRID]; int pidx[GRID];
  int psA[GRID]; int inA[GRID]; int unA[GRID];
};

// XLA expands logistic(x) as 0.5 + 0.5*tanh(0.5*x) — match that boundary.
__device__ __forceinline__ float sigmoid_ref(float x) {
  #pragma clang fp contract(off)
  return 0.5f + 0.5f * tanhf(0.5f * x);
}

// One grid barrier per iteration: tree-reduce {argmax, uncl, psum, inter},
// block 0 finishes across 512 slots, publishes results + next center/sigma.
__device__ void grid_reduce(Coord* __restrict__ c, const float* __restrict__ pred,
                            int b, int t, int tok,
                            float bv, int bi, int lu, int lps, int lin,
                            float* sv, int* si, int* sa, int* sb, int* sc)
{
  #pragma clang fp contract(off)
  sv[t] = bv; si[t] = bi; sa[t] = lu; sb[t] = lps; sc[t] = lin; __syncthreads();
  for (int off = BLOCK / 2; off; off >>= 1) {
    if (t < off) {
      float v = sv[t + off]; int ix = si[t + off];
      if (v > sv[t] || (v == sv[t] && ix < si[t])) { sv[t] = v; si[t] = ix; }
      sa[t] += sa[t + off]; sb[t] += sb[t + off]; sc[t] += sc[t + off];
    }
    __syncthreads();
  }
  if (t == 0) {
    c->pval[b] = sv[0]; c->pidx[b] = si[0];
    c->unA[b] = sa[0]; c->psA[b] = sb[0]; c->inA[b] = sc[0];
    __threadfence();   // payload visible before arrival token
    __hip_atomic_store(&c->arr[b], tok, __ATOMIC_RELAXED, __HIP_MEMORY_SCOPE_AGENT);
  }
  if (b == 0) {
    // 512 slots, 2 per thread
    while (__hip_atomic_load(&c->arr[t], __ATOMIC_RELAXED, __HIP_MEMORY_SCOPE_AGENT) < tok ||
           __hip_atomic_load(&c->arr[t + BLOCK], __ATOMIC_RELAXED, __HIP_MEMORY_SCOPE_AGENT) < tok)
      __builtin_amdgcn_s_sleep(1);
    __syncthreads();
    __threadfence();   // acquire: payload slots fresh
    float v1 = c->pval[t];         int i1 = c->pidx[t];
    float v2 = c->pval[t + BLOCK]; int i2 = c->pidx[t + BLOCK];
    if (v2 > v1 || (v2 == v1 && i2 < i1)) { v1 = v2; i1 = i2; }
    sv[t] = v1; si[t] = i1;
    sa[t] = c->unA[t] + c->unA[t + BLOCK];
    sb[t] = c->psA[t] + c->psA[t + BLOCK];
    sc[t] = c->inA[t] + c->inA[t + BLOCK];
    __syncthreads();
    for (int off = BLOCK / 2; off; off >>= 1) {
      if (t < off) {
        float v = sv[t + off]; int ix = si[t + off];
        if (v > sv[t] || (v == sv[t] && ix < si[t])) { sv[t] = v; si[t] = ix; }
        sa[t] += sa[t + off]; sb[t] += sb[t + off]; sc[t] += sc[t + off];
      }
      __syncthreads();
    }
    if (t == 0) {
      int sx = si[0];
      c->sval = sv[0]; c->sidx = sx; c->uncl = sa[0];
      c->psum = sb[0]; c->inter = sc[0];
      // center + sigma for the NEXT segment (identical math to reference)
      c->cx = tanhf(pred[sx])      + (2.0f / 2047.0f) * (float)(sx & (WW - 1));
      c->cy = tanhf(pred[NN + sx]) + (1.0f / 1023.0f) * (float)(sx >> 11);
      c->s0 = expf(pred[2 * NN + sx] * 10.0f);
      c->s1 = expf(pred[3 * NN + sx] * 10.0f);
      __threadfence();
      __hip_atomic_store(&c->flag, tok, __ATOMIC_RELAXED, __HIP_MEMORY_SCOPE_AGENT);
    }
  }
  if (t == 0)
    while (__hip_atomic_load(&c->flag, __ATOMIC_RELAXED, __HIP_MEMORY_SCOPE_AGENT) < tok)
      __builtin_amdgcn_s_sleep(1);
  __syncthreads();
  __threadfence();     // acquire: published fields fresh
}

__global__ void init_kernel(Coord* c) {
  int t = threadIdx.x;
  for (int s = t; s < GRID; s += blockDim.x) c->arr[s] = 0;
  if (t == 0) c->flag = 0;
}

__global__ __launch_bounds__(BLOCK, 2)
void cluster_kernel(const float* __restrict__ pred,
                    int* __restrict__ out,
                    Coord* __restrict__ c)
{
  #pragma clang fp contract(off)
  const int b = blockIdx.x, t = threadIdx.x;
  const int base = b * CHUNK;

  __shared__ float sv[BLOCK];
  __shared__ int   si[BLOCK], sa[BLOCK], sb[BLOCK], sc[BLOCK];

  const float xstep = 2.0f / 2047.0f;   // jnp.linspace(0,2,2048) step, f32
  const float ystep = 1.0f / 1023.0f;   // jnp.linspace(0,1,1024) step, f32

  // ---- stage 1: load once, keep everything in registers ----
  float ex[PXT], ey[PXT], sd[PXT];
  unsigned mbits = 0, ubits;
  float bv = -1.0f; int bi = 0; int mc = 0;
  #pragma unroll
  for (int k = 0; k < PXT; ++k) {
    int i = base + t + k * BLOCK;
    float seed = sigmoid_ref(pred[6 * NN + i]);
    sd[k] = seed;
    unsigned m = (seed > 0.5f) ? 1u : 0u;
    mbits |= m << k;
    ex[k] = tanhf(pred[i])      + xstep * (float)(i & (WW - 1));
    ey[k] = tanhf(pred[NN + i]) + ystep * (float)(i >> 11);
    out[i] = 0;
    mc += (int)m;
    float scv = m ? seed : 0.0f;
    if (scv > bv) { bv = scv; bi = i; }  // i increasing -> first max kept
  }
  ubits = mbits;

  int tok = 1;
  grid_reduce(c, pred, b, t, tok, bv, bi, mc, 0, 0, sv, si, sa, sb, sc); tok++;

  // ---- main loop: one barrier per iteration, zero bulk memory traffic ----
  int count = 1;
  unsigned prev_pr = 0;
  for (int it = 0; it < 8192; ++it) {
    int   sidx = c->sidx;  float sval = c->sval;  int un = c->uncl;
    float cx = c->cx, cy = c->cy, s0 = c->s0, s1 = c->s1;

    // deferred label write for the previous segment (before break checks!)
    if (it) {
      int psum = c->psum, inter = c->inter;
      bool accept = (psum > 160) &&
                    ((float)inter / (float)(psum > 1 ? psum : 1) > 0.5f);
      if (accept) {
        #pragma unroll
        for (int k = 0; k < PXT; ++k)
          if ((prev_pr >> k) & 1u) out[base + t + k * BLOCK] = count;
        count++;
      }
    }
    if (un <= 160) break;          // cond: uncl.sum() > min_pixel
    if (!(sval >= 0.5f)) break;    // go == false -> stop, no state change

    // seed-pixel bit within this thread's pixels (i = base + t + k*BLOCK)
    int rel = sidx - base;
    unsigned sbit = 0;
    if (rel >= 0 && rel < CHUNK && (rel & (BLOCK - 1)) == t)
      sbit = 1u << (rel >> 8);

    // proposal bits (decision-path math identical to reference)
    unsigned pr = 0;
    #pragma unroll
    for (int k = 0; k < PXT; ++k) {
      float dx = ex[k] - cx, dy = ey[k] - cy;
      float dsq = (dx * dx) * s0 + (dy * dy) * s1;
      float dist = expf(-dsq);
      pr |= ((dist > 0.5f) ? 1u : 0u) << k;
    }
    pr &= mbits;
    int lps = __popc(pr);
    int lin = __popc(pr & ubits & ~sbit);  // uncl2 & proposal
    ubits &= ~pr; ubits &= ~sbit;          // uncl_new
    int lu = __popc(ubits);

    // next-seed argmax over remaining unclustered (static indices only)
    bv = -1.0f; bi = 0;
    #pragma unroll
    for (int k = 0; k < PXT; ++k) {
      if (((ubits >> k) & 1u) && sd[k] > bv) { bv = sd[k]; bi = base + t + k * BLOCK; }
    }
    prev_pr = pr;
    grid_reduce(c, pred, b, t, tok, bv, bi, lu, lps, lin, sv, si, sa, sb, sc); tok++;
  }
}

extern "C" void kernel_launch(void* const* d_in, const int* in_sizes, int n_in,
                              void* d_out, int out_size, void* d_ws, size_t ws_size,
                              hipStream_t stream) {
  const float* pred = (const float*)d_in[0];
  int* out = (int*)d_out;
  Coord* c = (Coord*)d_ws;

  init_kernel<<<1, 256, 0, stream>>>(c);

  // Normal launch: co-residency of 512 blocks at 2 blocks/CU is guaranteed by
  // __launch_bounds__(256,2) (VGPR<=256, LDS 5KB) on 256 CUs — no cooperative
  // pre-check that can silently refuse the dispatch.
  cluster_kernel<<<dim3(GRID), dim3(BLOCK), 0, stream>>>(pred, out, c);
}

// Round 7
// 92.699 us; speedup vs baseline: 13.6295x; 4.7978x over previous
//
#include <hip/hip_runtime.h>

typedef unsigned long long u64;

#define HH 1024
#define WW 2048
#define NN (HH*WW)
#define GRID 512
#define BLOCK 256
#define PXT 16
#define CHUNK (PXT*BLOCK)       // 4096 pixels per block

// All cross-block traffic is tagged 64-bit relaxed atomics: (tok<<32 | payload).
// Same-address atomicity makes each slot self-validating -> ZERO fences.
struct Coord {
  u64 arr[GRID * 4];            // per-block: [0]=bv [1]=bi [2]=lps<<16|lin [3]=lu
  u64 pub[16];                  // [0]=sval [1]=sidx [2]=uncl [3]=psum [4]=inter
                                // [5]=cx [6]=cy [7]=s0 [8]=s1
};

// XLA expands logistic(x) as 0.5 + 0.5*tanh(0.5*x) — match that boundary.
__device__ __forceinline__ float sigmoid_ref(float x) {
  #pragma clang fp contract(off)
  return 0.5f + 0.5f * tanhf(0.5f * x);
}

__device__ __forceinline__ void slot_store(u64* p, int tok, unsigned v) {
  __hip_atomic_store(p, ((u64)(unsigned)tok << 32) | v,
                     __ATOMIC_RELAXED, __HIP_MEMORY_SCOPE_AGENT);
}
__device__ __forceinline__ unsigned slot_poll(u64* p, int tok) {
  u64 v = __hip_atomic_load(p, __ATOMIC_RELAXED, __HIP_MEMORY_SCOPE_AGENT);
  while ((unsigned)(v >> 32) != (unsigned)tok) {
    __builtin_amdgcn_s_sleep(1);
    v = __hip_atomic_load(p, __ATOMIC_RELAXED, __HIP_MEMORY_SCOPE_AGENT);
  }
  return (unsigned)v;
}

// Fence-free grid barrier + reduction + publish. Returns published values.
__device__ void barrier_exchange(Coord* __restrict__ c, const float* __restrict__ pred,
                                 int b, int t, int tok,
                                 float bv, int bi, int lu, int lps, int lin,
                                 float& sval, int& sidx, int& uncl, int& psum, int& inter,
                                 float& cx, float& cy, float& s0, float& s1)
{
  #pragma clang fp contract(off)
  __shared__ float wv[4];
  __shared__ int   wi[4], wu[4], wp[4], wn[4];
  __shared__ int   sx_sh;
  __shared__ unsigned pubv[9];
  const int w = t >> 6, lane = t & 63;

  // wave64 butterfly-down reduce (min-index tiebreak is order-independent)
  for (int off = 32; off; off >>= 1) {
    float v  = __shfl_down(bv, off);
    int   ix = __shfl_down(bi, off);
    int   a  = __shfl_down(lu, off);
    int   p2 = __shfl_down(lps, off);
    int   q2 = __shfl_down(lin, off);
    if (v > bv || (v == bv && ix < bi)) { bv = v; bi = ix; }
    lu += a; lps += p2; lin += q2;
  }
  if (lane == 0) { wv[w] = bv; wi[w] = bi; wu[w] = lu; wp[w] = lps; wn[w] = lin; }
  __syncthreads();
  if (t == 0) {
    float v0 = wv[0]; int i0 = wi[0]; int u0 = wu[0], p0 = wp[0], n0 = wn[0];
    for (int j = 1; j < 4; ++j) {
      if (wv[j] > v0 || (wv[j] == v0 && wi[j] < i0)) { v0 = wv[j]; i0 = wi[j]; }
      u0 += wu[j]; p0 += wp[j]; n0 += wn[j];
    }
    u64* s = &c->arr[b * 4];
    slot_store(s + 0, tok, __float_as_uint(v0));
    slot_store(s + 1, tok, (unsigned)i0);
    slot_store(s + 2, tok, ((unsigned)p0 << 16) | (unsigned)n0);
    slot_store(s + 3, tok, (unsigned)u0);
  }

  if (b == 0) {
    // gather: thread t owns blocks t and t+BLOCK (4 tagged slots each)
    u64* sA = &c->arr[t * 4];
    u64* sB = &c->arr[(t + BLOCK) * 4];
    float v1 = __uint_as_float(slot_poll(sA + 0, tok));
    int   i1 = (int)slot_poll(sA + 1, tok);
    unsigned pn1 = slot_poll(sA + 2, tok);
    int   u1 = (int)slot_poll(sA + 3, tok);
    float v2 = __uint_as_float(slot_poll(sB + 0, tok));
    int   i2 = (int)slot_poll(sB + 1, tok);
    unsigned pn2 = slot_poll(sB + 2, tok);
    int   u2 = (int)slot_poll(sB + 3, tok);
    if (v2 > v1 || (v2 == v1 && i2 < i1)) { v1 = v2; i1 = i2; }
    int lu2  = u1 + u2;
    int lps2 = (int)(pn1 >> 16) + (int)(pn2 >> 16);
    int lin2 = (int)(pn1 & 0xFFFFu) + (int)(pn2 & 0xFFFFu);
    for (int off = 32; off; off >>= 1) {
      float v  = __shfl_down(v1, off);
      int   ix = __shfl_down(i1, off);
      int   a  = __shfl_down(lu2, off);
      int   p2 = __shfl_down(lps2, off);
      int   q2 = __shfl_down(lin2, off);
      if (v > v1 || (v == v1 && ix < i1)) { v1 = v; i1 = ix; }
      lu2 += a; lps2 += p2; lin2 += q2;
    }
    if (lane == 0) { wv[w] = v1; wi[w] = i1; wu[w] = lu2; wp[w] = lps2; wn[w] = lin2; }
    __syncthreads();
    if (t == 0) {
      float v0 = wv[0]; int i0 = wi[0]; int u0 = wu[0], p0 = wp[0], n0 = wn[0];
      for (int j = 1; j < 4; ++j) {
        if (wv[j] > v0 || (wv[j] == v0 && wi[j] < i0)) { v0 = wv[j]; i0 = wi[j]; }
        u0 += wu[j]; p0 += wp[j]; n0 += wn[j];
      }
      wv[0] = v0; wu[0] = u0; wp[0] = p0; wn[0] = n0; sx_sh = i0;
    }
    __syncthreads();
    int sx = sx_sh;
    if (t == 0) {
      slot_store(&c->pub[0], tok, __float_as_uint(wv[0]));
      slot_store(&c->pub[1], tok, (unsigned)sx);
      slot_store(&c->pub[2], tok, (unsigned)wu[0]);
      slot_store(&c->pub[3], tok, (unsigned)wp[0]);
      slot_store(&c->pub[4], tok, (unsigned)wn[0]);
    } else if (t == 1) {
      float v = tanhf(pred[sx]) + (2.0f / 2047.0f) * (float)(sx & (WW - 1));
      slot_store(&c->pub[5], tok, __float_as_uint(v));
    } else if (t == 2) {
      float v = tanhf(pred[NN + sx]) + (1.0f / 1023.0f) * (float)(sx >> 11);
      slot_store(&c->pub[6], tok, __float_as_uint(v));
    } else if (t == 3) {
      float v = expf(pred[2 * NN + sx] * 10.0f);
      slot_store(&c->pub[7], tok, __float_as_uint(v));
    } else if (t == 4) {
      float v = expf(pred[3 * NN + sx] * 10.0f);
      slot_store(&c->pub[8], tok, __float_as_uint(v));
    }
  }

  // consume (all blocks, including 0): 9 threads poll in parallel
  if (t < 9) pubv[t] = slot_poll(&c->pub[t], tok);
  __syncthreads();
  sval = __uint_as_float(pubv[0]); sidx = (int)pubv[1]; uncl = (int)pubv[2];
  psum = (int)pubv[3]; inter = (int)pubv[4];
  cx = __uint_as_float(pubv[5]); cy = __uint_as_float(pubv[6]);
  s0 = __uint_as_float(pubv[7]); s1 = __uint_as_float(pubv[8]);
}

__global__ void init_kernel(Coord* c) {
  int t = threadIdx.x;
  u64* p = (u64*)c;
  for (int s = t; s < GRID * 4 + 16; s += blockDim.x) p[s] = 0;
}

__global__ __launch_bounds__(BLOCK, 2)
void cluster_kernel(const float* __restrict__ pred,
                    int* __restrict__ out,
                    Coord* __restrict__ c)
{
  #pragma clang fp contract(off)
  const int b = blockIdx.x, t = threadIdx.x;
  const int base = b * CHUNK;

  const float xstep = 2.0f / 2047.0f;   // jnp.linspace(0,2,2048) step, f32
  const float ystep = 1.0f / 1023.0f;   // jnp.linspace(0,1,1024) step, f32

  // ---- stage 1: load once, keep everything in registers ----
  float ex[PXT], ey[PXT], sd[PXT];
  unsigned mbits = 0, ubits;
  float bv = -1.0f; int bi = 0; int mc = 0;
  #pragma unroll
  for (int k = 0; k < PXT; ++k) {
    int i = base + t + k * BLOCK;
    float seed = sigmoid_ref(pred[6 * NN + i]);
    sd[k] = seed;
    unsigned m = (seed > 0.5f) ? 1u : 0u;
    mbits |= m << k;
    ex[k] = tanhf(pred[i])      + xstep * (float)(i & (WW - 1));
    ey[k] = tanhf(pred[NN + i]) + ystep * (float)(i >> 11);
    out[i] = 0;
    mc += (int)m;
    float scv = m ? seed : 0.0f;
    if (scv > bv) { bv = scv; bi = i; }  // i increasing -> first max kept
  }
  ubits = mbits;

  float sval, cx, cy, s0, s1; int sidx, un, psum, inter;
  int tok = 1;
  barrier_exchange(c, pred, b, t, tok, bv, bi, mc, 0, 0,
                   sval, sidx, un, psum, inter, cx, cy, s0, s1); tok++;

  // ---- main loop: one fence-free barrier per iteration ----
  int count = 1;
  unsigned prev_pr = 0;
  for (int it = 0; it < 8192; ++it) {
    // deferred label write for the previous segment (before break checks!)
    if (it) {
      bool accept = (psum > 160) &&
                    ((float)inter / (float)(psum > 1 ? psum : 1) > 0.5f);
      if (accept) {
        #pragma unroll
        for (int k = 0; k < PXT; ++k)
          if ((prev_pr >> k) & 1u) out[base + t + k * BLOCK] = count;
        count++;
      }
    }
    if (un <= 160) break;          // cond: uncl.sum() > min_pixel
    if (!(sval >= 0.5f)) break;    // go == false -> stop, no state change

    // seed-pixel bit within this thread's pixels (i = base + t + k*BLOCK)
    int rel = sidx - base;
    unsigned sbit = 0;
    if (rel >= 0 && rel < CHUNK && (rel & (BLOCK - 1)) == t)
      sbit = 1u << (rel >> 8);

    // proposal bits (decision-path math identical to reference)
    unsigned pr = 0;
    #pragma unroll
    for (int k = 0; k < PXT; ++k) {
      float dx = ex[k] - cx, dy = ey[k] - cy;
      float dsq = (dx * dx) * s0 + (dy * dy) * s1;
      float dist = expf(-dsq);
      pr |= ((dist > 0.5f) ? 1u : 0u) << k;
    }
    pr &= mbits;
    int lps = __popc(pr);
    int lin = __popc(pr & ubits & ~sbit);  // uncl2 & proposal
    ubits &= ~pr; ubits &= ~sbit;          // uncl_new
    int lu = __popc(ubits);

    // next-seed argmax over remaining unclustered (static indices only)
    bv = -1.0f; bi = 0;
    #pragma unroll
    for (int k = 0; k < PXT; ++k) {
      if (((ubits >> k) & 1u) && sd[k] > bv) { bv = sd[k]; bi = base + t + k * BLOCK; }
    }
    prev_pr = pr;
    barrier_exchange(c, pred, b, t, tok, bv, bi, lu, lps, lin,
                     sval, sidx, un, psum, inter, cx, cy, s0, s1); tok++;
  }
}

extern "C" void kernel_launch(void* const* d_in, const int* in_sizes, int n_in,
                              void* d_out, int out_size, void* d_ws, size_t ws_size,
                              hipStream_t stream) {
  const float* pred = (const float*)d_in[0];
  int* out = (int*)d_out;
  Coord* c = (Coord*)d_ws;

  init_kernel<<<1, 256, 0, stream>>>(c);

  // Normal launch: co-residency of 512 blocks at 2 blocks/CU is guaranteed by
  // __launch_bounds__(256,2) (VGPR<=256, small LDS) on 256 CUs.
  cluster_kernel<<<dim3(GRID), dim3(BLOCK), 0, stream>>>(pred, out, c);
}